// Round 3
// baseline (1332.871 us; speedup 1.0000x reference)
//
#include <hip/hip_runtime.h>
#include <hip/hip_bf16.h>
#include <math.h>

#define B_ 32
#define T_ 512
#define D_ 768
#define S_ 64
#define V_ 30522
#define C_ 16
#define INV_SQRT_D 0.03608439182435161f
#define SCORE_CLIP_ 20.0f

// ---------------------------------------------------------------------------
// M init: M[b,s,d] = mem_init[s,d]
__global__ __launch_bounds__(256) void k_initM(const float* __restrict__ mem_init,
                                               float* __restrict__ Mm) {
    const int i = blockIdx.x * 256 + threadIdx.x;        // float4 index
    const int per = S_ * D_ / 4;                         // 12288
    const float4 v = *(const float4*)(mem_init + (size_t)(i % per) * 4);
    *(float4*)(Mm + (size_t)i * 4) = v;
}

// ---------------------------------------------------------------------------
// Fused embedding-gather + dual GEMM: Qt = x@Wq, Vt = x@Wv
// x[r,k] = tok_emb[ids[r]][k] + pos_emb[r%T][k],  r in [0, B*T)
__global__ __launch_bounds__(256) void k_embed_qv(
    const int* __restrict__ ids, const float* __restrict__ tok_emb,
    const float* __restrict__ pos_emb, const float* __restrict__ Wq,
    const float* __restrict__ Wv, float* __restrict__ Qt, float* __restrict__ Vt)
{
    __shared__ float sA[16][64];    // [k][m]
    __shared__ float sBq[16][64];   // [k][n]
    __shared__ float sBv[16][64];
    __shared__ int   sIds[64];
    const int tid  = threadIdx.x;
    const int row0 = blockIdx.x * 64;
    const int col0 = blockIdx.y * 64;
    if (tid < 64) sIds[tid] = ids[row0 + tid];
    __syncthreads();
    const int tr = tid >> 4, tc = tid & 15;
    const int lrow = tid >> 2, lk = (tid & 3) << 2;   // 64 rows x 16 k loader
    const int bk = tid >> 4, bn = (tid & 15) << 2;    // 16 k  x 64 n loader
    float accQ[4][4] = {{0.f}}, accV[4][4] = {{0.f}};
    const int id = sIds[lrow];
    const int tpos = (row0 + lrow) & (T_ - 1);
    for (int k0 = 0; k0 < D_; k0 += 16) {
        {
            const float4 te = *(const float4*)(tok_emb + (size_t)id * D_ + k0 + lk);
            const float4 pe = *(const float4*)(pos_emb + (size_t)tpos * D_ + k0 + lk);
            sA[lk + 0][lrow] = te.x + pe.x;
            sA[lk + 1][lrow] = te.y + pe.y;
            sA[lk + 2][lrow] = te.z + pe.z;
            sA[lk + 3][lrow] = te.w + pe.w;
        }
        {
            *(float4*)&sBq[bk][bn] = *(const float4*)(Wq + (size_t)(k0 + bk) * D_ + col0 + bn);
            *(float4*)&sBv[bk][bn] = *(const float4*)(Wv + (size_t)(k0 + bk) * D_ + col0 + bn);
        }
        __syncthreads();
        #pragma unroll
        for (int kk = 0; kk < 16; ++kk) {
            const float4 a  = *(const float4*)&sA[kk][tr << 2];
            const float4 bq = *(const float4*)&sBq[kk][tc << 2];
            const float4 bv = *(const float4*)&sBv[kk][tc << 2];
            const float av[4]  = {a.x, a.y, a.z, a.w};
            const float bqv[4] = {bq.x, bq.y, bq.z, bq.w};
            const float bvv[4] = {bv.x, bv.y, bv.z, bv.w};
            #pragma unroll
            for (int i = 0; i < 4; ++i)
                #pragma unroll
                for (int j = 0; j < 4; ++j) {
                    accQ[i][j] = fmaf(av[i], bqv[j], accQ[i][j]);
                    accV[i][j] = fmaf(av[i], bvv[j], accV[i][j]);
                }
        }
        __syncthreads();
    }
    #pragma unroll
    for (int i = 0; i < 4; ++i) {
        const size_t r = (size_t)(row0 + (tr << 2) + i) * D_ + col0 + (tc << 2);
        #pragma unroll
        for (int j = 0; j < 4; ++j) { Qt[r + j] = accQ[i][j]; Vt[r + j] = accV[i][j]; }
    }
}

// ---------------------------------------------------------------------------
// Generic C = A @ Bm  (A: Mrows x 768 row-major, Bm: 768 x 768 row-major)
__global__ __launch_bounds__(256) void k_gemm(
    const float* __restrict__ A, const float* __restrict__ Bm,
    float* __restrict__ Cm)
{
    __shared__ float sA[16][64];
    __shared__ float sB[16][64];
    const int tid  = threadIdx.x;
    const int row0 = blockIdx.x * 64;
    const int col0 = blockIdx.y * 64;
    const int tr = tid >> 4, tc = tid & 15;
    const int lrow = tid >> 2, lk = (tid & 3) << 2;
    const int bk = tid >> 4, bn = (tid & 15) << 2;
    float acc[4][4] = {{0.f}};
    for (int k0 = 0; k0 < D_; k0 += 16) {
        {
            const float4 a = *(const float4*)(A + (size_t)(row0 + lrow) * D_ + k0 + lk);
            sA[lk + 0][lrow] = a.x;
            sA[lk + 1][lrow] = a.y;
            sA[lk + 2][lrow] = a.z;
            sA[lk + 3][lrow] = a.w;
        }
        *(float4*)&sB[bk][bn] = *(const float4*)(Bm + (size_t)(k0 + bk) * D_ + col0 + bn);
        __syncthreads();
        #pragma unroll
        for (int kk = 0; kk < 16; ++kk) {
            const float4 a = *(const float4*)&sA[kk][tr << 2];
            const float4 b = *(const float4*)&sB[kk][tc << 2];
            const float av[4] = {a.x, a.y, a.z, a.w};
            const float bv[4] = {b.x, b.y, b.z, b.w};
            #pragma unroll
            for (int i = 0; i < 4; ++i)
                #pragma unroll
                for (int j = 0; j < 4; ++j)
                    acc[i][j] = fmaf(av[i], bv[j], acc[i][j]);
        }
        __syncthreads();
    }
    #pragma unroll
    for (int i = 0; i < 4; ++i) {
        const size_t r = (size_t)(row0 + (tr << 2) + i) * D_ + col0 + (tc << 2);
        #pragma unroll
        for (int j = 0; j < 4; ++j) Cm[r + j] = acc[i][j];
    }
}

// ---------------------------------------------------------------------------
// scores[t,s] = clip(Qt[b,t,:]·Km[b,s,:] * inv_sqrt_d), softmax over s -> W
__global__ __launch_bounds__(256) void k_scores(
    const float* __restrict__ Qt, const float* __restrict__ Km,
    const int* __restrict__ amask, float* __restrict__ Wout)
{
    __shared__ float sQ[16][64];   // [k][t]
    __shared__ float sK[16][64];   // [k][s]
    __shared__ float ssc[64][65];  // [t][s]
    const int tid = threadIdx.x;
    const int b  = blockIdx.y;
    const int t0 = blockIdx.x * 64;
    const int tr = tid >> 4, tc = tid & 15;
    const int lrow = tid >> 2, lk = (tid & 3) << 2;
    const float* Qb = Qt + (size_t)b * T_ * D_;
    const float* Kb = Km + (size_t)b * S_ * D_;
    float acc[4][4] = {{0.f}};
    for (int k0 = 0; k0 < D_; k0 += 16) {
        {
            const float4 q = *(const float4*)(Qb + (size_t)(t0 + lrow) * D_ + k0 + lk);
            sQ[lk + 0][lrow] = q.x; sQ[lk + 1][lrow] = q.y;
            sQ[lk + 2][lrow] = q.z; sQ[lk + 3][lrow] = q.w;
            const float4 kv = *(const float4*)(Kb + (size_t)lrow * D_ + k0 + lk);
            sK[lk + 0][lrow] = kv.x; sK[lk + 1][lrow] = kv.y;
            sK[lk + 2][lrow] = kv.z; sK[lk + 3][lrow] = kv.w;
        }
        __syncthreads();
        #pragma unroll
        for (int kk = 0; kk < 16; ++kk) {
            const float4 a = *(const float4*)&sQ[kk][tr << 2];
            const float4 k4 = *(const float4*)&sK[kk][tc << 2];
            const float av[4] = {a.x, a.y, a.z, a.w};
            const float kv[4] = {k4.x, k4.y, k4.z, k4.w};
            #pragma unroll
            for (int i = 0; i < 4; ++i)
                #pragma unroll
                for (int j = 0; j < 4; ++j)
                    acc[i][j] = fmaf(av[i], kv[j], acc[i][j]);
        }
        __syncthreads();
    }
    #pragma unroll
    for (int i = 0; i < 4; ++i)
        #pragma unroll
        for (int j = 0; j < 4; ++j) {
            float v = acc[i][j] * INV_SQRT_D;
            v = fminf(fmaxf(v, -SCORE_CLIP_), SCORE_CLIP_);
            ssc[(tr << 2) + i][(tc << 2) + j] = v;
        }
    __syncthreads();
    // softmax over s: 4 threads per row
    const int row = tid >> 2, qq = tid & 3;
    float vals[16];
    float mx = -1e30f;
    #pragma unroll
    for (int jj = 0; jj < 16; ++jj) {
        vals[jj] = ssc[row][qq + (jj << 2)];
        mx = fmaxf(mx, vals[jj]);
    }
    mx = fmaxf(mx, __shfl_xor(mx, 1));
    mx = fmaxf(mx, __shfl_xor(mx, 2));
    float sum = 0.f;
    #pragma unroll
    for (int jj = 0; jj < 16; ++jj) {
        vals[jj] = expf(vals[jj] - mx);
        sum += vals[jj];
    }
    sum += __shfl_xor(sum, 1);
    sum += __shfl_xor(sum, 2);
    const int t = t0 + row;
    const float mrow = (amask[b * T_ + t] > 0) ? 1.0f : 0.0f;
    const float inv = mrow / sum;
    float* Wrow = Wout + ((size_t)b * T_ + t) * S_;
    #pragma unroll
    for (int jj = 0; jj < 16; ++jj)
        Wrow[qq + (jj << 2)] = vals[jj] * inv;
}

// ---------------------------------------------------------------------------
// write[s,d] = sum_t W[t,s]*Vt[t,d];  M = clip(0.9*M + 0.1*write, +-50)
__global__ __launch_bounds__(256) void k_write(
    const float* __restrict__ Wm, const float* __restrict__ Vt,
    float* __restrict__ Mm)
{
    __shared__ float sW[16][64];   // [t][s]
    __shared__ float sV[16][64];   // [t][d]
    const int tid = threadIdx.x;
    const int b    = blockIdx.y;
    const int col0 = blockIdx.x * 64;
    const int tr = tid >> 4, tc = tid & 15;
    const int lt = tid >> 4, lc = (tid & 15) << 2;
    const float* Wb = Wm + (size_t)b * T_ * S_;
    const float* Vb = Vt + (size_t)b * T_ * D_;
    float acc[4][4] = {{0.f}};
    for (int t0 = 0; t0 < T_; t0 += 16) {
        *(float4*)&sW[lt][lc] = *(const float4*)(Wb + (size_t)(t0 + lt) * S_ + lc);
        *(float4*)&sV[lt][lc] = *(const float4*)(Vb + (size_t)(t0 + lt) * D_ + col0 + lc);
        __syncthreads();
        #pragma unroll
        for (int kk = 0; kk < 16; ++kk) {
            const float4 a = *(const float4*)&sW[kk][tr << 2];
            const float4 v = *(const float4*)&sV[kk][tc << 2];
            const float av[4] = {a.x, a.y, a.z, a.w};
            const float vv[4] = {v.x, v.y, v.z, v.w};
            #pragma unroll
            for (int i = 0; i < 4; ++i)
                #pragma unroll
                for (int j = 0; j < 4; ++j)
                    acc[i][j] = fmaf(av[i], vv[j], acc[i][j]);
        }
        __syncthreads();
    }
    #pragma unroll
    for (int i = 0; i < 4; ++i) {
        const size_t idx0 = ((size_t)b * S_ + (tr << 2) + i) * D_ + col0 + (tc << 2);
        #pragma unroll
        for (int j = 0; j < 4; ++j) {
            float m = Mm[idx0 + j];
            m = 0.9f * m + 0.1f * acc[i][j];
            Mm[idx0 + j] = fminf(fmaxf(m, -50.f), 50.f);
        }
    }
}

// ---------------------------------------------------------------------------
// Wbar[b,s] = (sum_t W[b,t,s]) / max(valid_b, 1)
__global__ __launch_bounds__(64) void k_wbar(
    const float* __restrict__ Wm, const int* __restrict__ amask,
    float* __restrict__ Wbar)
{
    const int b = blockIdx.x, s = threadIdx.x;
    const float* Wb = Wm + (size_t)b * T_ * S_;
    float sum = 0.f;
    for (int t = 0; t < T_; ++t) sum += Wb[(size_t)t * S_ + s];
    int v = 0;
    for (int t = s; t < T_; t += 64) v += (amask[b * T_ + t] > 0) ? 1 : 0;
    #pragma unroll
    for (int o = 1; o < 64; o <<= 1) v += __shfl_xor(v, o);
    Wbar[b * S_ + s] = sum / fmaxf((float)v, 1.0f);
}

// ---------------------------------------------------------------------------
// pooled = Wbar @ M; LN; logits = pooled @ cls_w + cls_b; nan_to_num
__global__ __launch_bounds__(256) void k_head(
    const float* __restrict__ Wbar, const float* __restrict__ Mm,
    const float* __restrict__ ln_scale, const float* __restrict__ ln_bias,
    const float* __restrict__ cls_w, const float* __restrict__ cls_b,
    float* __restrict__ out)
{
    __shared__ float sw[64];
    __shared__ float sp[768];
    __shared__ float sred[4];
    __shared__ float sl[16][17];
    const int b = blockIdx.x, tid = threadIdx.x;
    if (tid < 64) sw[tid] = Wbar[b * S_ + tid];
    __syncthreads();
    float p[3] = {0.f, 0.f, 0.f};
    const float* Mb = Mm + (size_t)b * S_ * D_;
    for (int s = 0; s < S_; ++s) {
        const float wv = sw[s];
        const float* Mr = Mb + (size_t)s * D_;
        #pragma unroll
        for (int jj = 0; jj < 3; ++jj)
            p[jj] = fmaf(wv, Mr[tid + (jj << 8)], p[jj]);
    }
    // mean
    float lsum = p[0] + p[1] + p[2];
    #pragma unroll
    for (int o = 1; o < 64; o <<= 1) lsum += __shfl_xor(lsum, o);
    if ((tid & 63) == 0) sred[tid >> 6] = lsum;
    __syncthreads();
    const float mean = (sred[0] + sred[1] + sred[2] + sred[3]) * (1.0f / 768.0f);
    // var
    float lv = 0.f;
    #pragma unroll
    for (int jj = 0; jj < 3; ++jj) { const float d = p[jj] - mean; lv += d * d; }
    #pragma unroll
    for (int o = 1; o < 64; o <<= 1) lv += __shfl_xor(lv, o);
    __syncthreads();   // everyone done reading sred for mean
    if ((tid & 63) == 0) sred[tid >> 6] = lv;
    __syncthreads();
    const float var = (sred[0] + sred[1] + sred[2] + sred[3]) * (1.0f / 768.0f);
    const float inv = 1.0f / sqrtf(var + 1e-5f);
    #pragma unroll
    for (int jj = 0; jj < 3; ++jj) {
        const int d = tid + (jj << 8);
        sp[d] = (p[jj] - mean) * inv * ln_scale[d] + ln_bias[d];
    }
    __syncthreads();
    // logits
    const int c = tid & 15, g = tid >> 4;
    float part = 0.f;
    const int d0 = g * 48;
    for (int d = d0; d < d0 + 48; ++d)
        part = fmaf(sp[d], cls_w[(size_t)d * C_ + c], part);
    sl[g][c] = part;
    __syncthreads();
    if (tid < 16) {
        float sum = cls_b[tid];
        #pragma unroll
        for (int g2 = 0; g2 < 16; ++g2) sum += sl[g2][tid];
        if (isnan(sum) || isinf(sum)) sum = 0.f;
        out[b * C_ + tid] = sum;
    }
}

// ---------------------------------------------------------------------------
extern "C" void kernel_launch(void* const* d_in, const int* in_sizes, int n_in,
                              void* d_out, int out_size, void* d_ws, size_t ws_size,
                              hipStream_t stream) {
    (void)in_sizes; (void)n_in; (void)out_size; (void)ws_size;
    const int*   ids      = (const int*)d_in[0];
    const int*   amask    = (const int*)d_in[1];
    const float* tok_emb  = (const float*)d_in[2];
    const float* pos_emb  = (const float*)d_in[3];
    const float* Wq       = (const float*)d_in[4];
    const float* Wk       = (const float*)d_in[5];
    const float* Wv       = (const float*)d_in[6];
    const float* mem_init = (const float*)d_in[7];
    const float* ln_scale = (const float*)d_in[8];
    const float* ln_bias  = (const float*)d_in[9];
    const float* cls_w    = (const float*)d_in[10];
    const float* cls_b    = (const float*)d_in[11];

    float* ws   = (float*)d_ws;
    float* Qt   = ws;
    float* Vt   = Qt + (size_t)B_ * T_ * D_;
    float* Mm   = Vt + (size_t)B_ * T_ * D_;
    float* Km   = Mm + (size_t)B_ * S_ * D_;
    float* Wm   = Km + (size_t)B_ * S_ * D_;
    float* Wbar = Wm + (size_t)B_ * T_ * S_;

    k_initM<<<B_ * S_ * D_ / 4 / 256, 256, 0, stream>>>(mem_init, Mm);
    k_embed_qv<<<dim3(B_ * T_ / 64, D_ / 64), 256, 0, stream>>>(
        ids, tok_emb, pos_emb, Wq, Wv, Qt, Vt);
    for (int step = 0; step < 4; ++step) {
        k_gemm<<<dim3(B_ * S_ / 64, D_ / 64), 256, 0, stream>>>(Mm, Wk, Km);
        k_scores<<<dim3(T_ / 64, B_), 256, 0, stream>>>(Qt, Km, amask, Wm);
        k_write<<<dim3(D_ / 64, B_), 256, 0, stream>>>(Wm, Vt, Mm);
    }
    k_gemm<<<dim3(B_ * S_ / 64, D_ / 64), 256, 0, stream>>>(Mm, Wk, Km);
    k_scores<<<dim3(T_ / 64, B_), 256, 0, stream>>>(Qt, Km, amask, Wm);
    k_wbar<<<B_, 64, 0, stream>>>(Wm, amask, Wbar);
    k_head<<<B_, 256, 0, stream>>>(Wbar, Mm, ln_scale, ln_bias, cls_w, cls_b,
                                   (float*)d_out);
}

// Round 4
// 486.861 us; speedup vs baseline: 2.7377x; 2.7377x over previous
//
#include <hip/hip_runtime.h>
#include <math.h>

#define B_ 32
#define T_ 512
#define D_ 768
#define S_ 64
#define C_ 16
#define INV_SQRT_D 0.03608439182435161f
#define SCORE_CLIP_ 20.0f

typedef __attribute__((ext_vector_type(8))) short short8;
typedef __attribute__((ext_vector_type(4))) float f32x4;

// RNE float->bf16
static __device__ __forceinline__ unsigned short f2bf(float f) {
    union { float f; unsigned u; } v; v.f = f;
    unsigned r = v.u + 0x7fffu + ((v.u >> 16) & 1u);
    return (unsigned short)(r >> 16);
}
static __device__ __forceinline__ unsigned pk2(float a, float b) {
    return (unsigned)f2bf(a) | ((unsigned)f2bf(b) << 16);
}

// ---------------------------------------------------------------------------
// Wt[n][k] = bf16(W[k][n]) for Wq, Wk, Wv
__global__ __launch_bounds__(256) void k_prep(
    const float* __restrict__ Wq, const float* __restrict__ Wk,
    const float* __restrict__ Wv, unsigned short* __restrict__ Wtq,
    unsigned short* __restrict__ Wtk, unsigned short* __restrict__ Wtv)
{
    const int flat = blockIdx.x * 256 + threadIdx.x;   // n*768 + k
    const int n = flat / 768, k = flat - n * 768;
    const float* src = (blockIdx.y == 0) ? Wq : (blockIdx.y == 1) ? Wk : Wv;
    unsigned short* dst = (blockIdx.y == 0) ? Wtq : (blockIdx.y == 1) ? Wtk : Wtv;
    dst[flat] = f2bf(src[(size_t)k * D_ + n]);
}

// ---------------------------------------------------------------------------
// M[b][s][d] = mem_init[s][d] (fp32)
__global__ __launch_bounds__(256) void k_initM(const float* __restrict__ mem_init,
                                               float* __restrict__ Mm) {
    const int i = blockIdx.x * 256 + threadIdx.x;        // float4 index
    const int per = S_ * D_ / 4;
    const float4 v = *(const float4*)(mem_init + (size_t)(i % per) * 4);
    *(float4*)(Mm + (size_t)i * 4) = v;
}

// ---------------------------------------------------------------------------
// X[r][d] = bf16(tok_emb[ids[r]][d] + pos_emb[r%512][d])
__global__ __launch_bounds__(256) void k_embed_x(
    const int* __restrict__ ids, const float* __restrict__ tok_emb,
    const float* __restrict__ pos_emb, unsigned short* __restrict__ Xb)
{
    const int idx = blockIdx.x * 256 + threadIdx.x;      // chunk of 8 elems
    const int r = idx / 96, c = (idx - r * 96) * 8;
    const int id = ids[r], tp = r & (T_ - 1);
    const float* te = tok_emb + (size_t)id * D_ + c;
    const float* pe = pos_emb + (size_t)tp * D_ + c;
    const float4 a0 = *(const float4*)te, a1 = *(const float4*)(te + 4);
    const float4 p0 = *(const float4*)pe, p1 = *(const float4*)(pe + 4);
    uint4 u;
    u.x = pk2(a0.x + p0.x, a0.y + p0.y);
    u.y = pk2(a0.z + p0.z, a0.w + p0.w);
    u.z = pk2(a1.x + p1.x, a1.y + p1.y);
    u.w = pk2(a1.z + p1.z, a1.w + p1.w);
    *(uint4*)(Xb + (size_t)idx * 8) = u;
}

// ---------------------------------------------------------------------------
// Dual GEMM: Qt[t][n] = X@Wq (natural), Vtt[b][d][t] = (X@Wv)^T. 128x128 tile.
__global__ __launch_bounds__(256) void k_qv(
    const unsigned short* __restrict__ Xb, const unsigned short* __restrict__ Wtq,
    const unsigned short* __restrict__ Wtv, unsigned short* __restrict__ Qt,
    unsigned short* __restrict__ Vtt)
{
    __shared__ unsigned short sX[128][40];
    __shared__ unsigned short sQ[128][40];
    __shared__ unsigned short sV[128][40];
    const int tid = threadIdx.x;
    const int row0 = blockIdx.x * 128;   // token rows
    const int col0 = blockIdx.y * 128;   // n cols
    const int lane = tid & 63, w = tid >> 6;
    const int wm = w >> 1, wn = w & 1;
    const int q = lane >> 4, lr = lane & 15;
    f32x4 accq[4][4], accv[4][4];
    #pragma unroll
    for (int i = 0; i < 4; ++i)
        #pragma unroll
        for (int j = 0; j < 4; ++j) {
            accq[i][j] = (f32x4){0.f, 0.f, 0.f, 0.f};
            accv[i][j] = (f32x4){0.f, 0.f, 0.f, 0.f};
        }
    for (int k0 = 0; k0 < D_; k0 += 32) {
        __syncthreads();
        #pragma unroll
        for (int cc = 0; cc < 2; ++cc) {
            const int c = tid + cc * 256;
            const int row = c >> 2, ch = c & 3;
            *(uint4*)&sX[row][ch * 8] =
                *(const uint4*)(Xb + (size_t)(row0 + row) * D_ + k0 + ch * 8);
            *(uint4*)&sQ[row][ch * 8] =
                *(const uint4*)(Wtq + (size_t)(col0 + row) * D_ + k0 + ch * 8);
            *(uint4*)&sV[row][ch * 8] =
                *(const uint4*)(Wtv + (size_t)(col0 + row) * D_ + k0 + ch * 8);
        }
        __syncthreads();
        short8 a[4], bq[4], bv[4];
        #pragma unroll
        for (int i = 0; i < 4; ++i) {
            a[i]  = *(const short8*)&sX[wm * 64 + i * 16 + lr][q * 8];
            bq[i] = *(const short8*)&sQ[wn * 64 + i * 16 + lr][q * 8];
            bv[i] = *(const short8*)&sV[wn * 64 + i * 16 + lr][q * 8];
        }
        #pragma unroll
        for (int i = 0; i < 4; ++i)
            #pragma unroll
            for (int j = 0; j < 4; ++j) {
                accq[i][j] = __builtin_amdgcn_mfma_f32_16x16x32_bf16(a[i], bq[j], accq[i][j], 0, 0, 0);
                accv[i][j] = __builtin_amdgcn_mfma_f32_16x16x32_bf16(a[i], bv[j], accv[i][j], 0, 0, 0);
            }
    }
    const int b = row0 >> 9;
    #pragma unroll
    for (int i = 0; i < 4; ++i)
        #pragma unroll
        for (int j = 0; j < 4; ++j) {
            const int gr = row0 + wm * 64 + i * 16 + 4 * q;   // token row
            const int gc = col0 + wn * 64 + j * 16 + lr;      // n col
            #pragma unroll
            for (int r = 0; r < 4; ++r)
                Qt[(size_t)(gr + r) * D_ + gc] = f2bf(accq[i][j][r]);
            uint2 u;
            u.x = pk2(accv[i][j][0], accv[i][j][1]);
            u.y = pk2(accv[i][j][2], accv[i][j][3]);
            const int t = (gr & (T_ - 1));
            *(uint2*)(Vtt + ((size_t)b * D_ + gc) * T_ + t) = u;
        }
}

// ---------------------------------------------------------------------------
// Km[b][s][d] = bf16( M[b] @ Wk ).  64x64 tile per block; 4 waves (2x2 of 32x32).
__global__ __launch_bounds__(256) void k_km(
    const float* __restrict__ Mm, const unsigned short* __restrict__ Wtk,
    unsigned short* __restrict__ Km)
{
    __shared__ unsigned short sA[64][40];
    __shared__ unsigned short sB[64][40];
    const int tid = threadIdx.x;
    const int d0 = blockIdx.x * 64;
    const int b = blockIdx.y;
    const int lane = tid & 63, w = tid >> 6;
    const int wm = w >> 1, wn = w & 1;
    const int q = lane >> 4, lr = lane & 15;
    const int row = tid >> 2, ch = tid & 3;
    f32x4 acc[2][2];
    #pragma unroll
    for (int i = 0; i < 2; ++i)
        #pragma unroll
        for (int j = 0; j < 2; ++j) acc[i][j] = (f32x4){0.f, 0.f, 0.f, 0.f};
    for (int k0 = 0; k0 < D_; k0 += 32) {
        __syncthreads();
        {
            const float* src = Mm + ((size_t)b * S_ + row) * D_ + k0 + ch * 8;
            const float4 x0 = *(const float4*)src, x1 = *(const float4*)(src + 4);
            uint4 u;
            u.x = pk2(x0.x, x0.y); u.y = pk2(x0.z, x0.w);
            u.z = pk2(x1.x, x1.y); u.w = pk2(x1.z, x1.w);
            *(uint4*)&sA[row][ch * 8] = u;
            *(uint4*)&sB[row][ch * 8] =
                *(const uint4*)(Wtk + (size_t)(d0 + row) * D_ + k0 + ch * 8);
        }
        __syncthreads();
        short8 a[2], bb[2];
        #pragma unroll
        for (int i = 0; i < 2; ++i) {
            a[i]  = *(const short8*)&sA[wm * 32 + i * 16 + lr][q * 8];
            bb[i] = *(const short8*)&sB[wn * 32 + i * 16 + lr][q * 8];
        }
        #pragma unroll
        for (int i = 0; i < 2; ++i)
            #pragma unroll
            for (int j = 0; j < 2; ++j)
                acc[i][j] = __builtin_amdgcn_mfma_f32_16x16x32_bf16(a[i], bb[j], acc[i][j], 0, 0, 0);
    }
    #pragma unroll
    for (int i = 0; i < 2; ++i)
        #pragma unroll
        for (int j = 0; j < 2; ++j)
            #pragma unroll
            for (int r = 0; r < 4; ++r) {
                const int s = wm * 32 + i * 16 + 4 * q + r;
                const int d = d0 + wn * 32 + j * 16 + lr;
                Km[((size_t)b * S_ + s) * D_ + d] = f2bf(acc[i][j][r]);
            }
}

// ---------------------------------------------------------------------------
// scores -> softmax -> Wst[b][s][t] (fp32, transposed). Tile 64 t x 64 s (all s).
__global__ __launch_bounds__(256) void k_scores(
    const unsigned short* __restrict__ Qt, const unsigned short* __restrict__ Km,
    const int* __restrict__ amask, float* __restrict__ Wst)
{
    __shared__ unsigned short sQ[64][40];
    __shared__ unsigned short sK[64][40];
    __shared__ float ssc[64][65];
    const int tid = threadIdx.x;
    const int t0 = blockIdx.x * 64;
    const int b = blockIdx.y;
    const int lane = tid & 63, w = tid >> 6;
    const int wm = w >> 1, wn = w & 1;
    const int q = lane >> 4, lr = lane & 15;
    const int row = tid >> 2, ch = tid & 3;
    f32x4 acc[2][2];
    #pragma unroll
    for (int i = 0; i < 2; ++i)
        #pragma unroll
        for (int j = 0; j < 2; ++j) acc[i][j] = (f32x4){0.f, 0.f, 0.f, 0.f};
    for (int k0 = 0; k0 < D_; k0 += 32) {
        __syncthreads();
        *(uint4*)&sQ[row][ch * 8] =
            *(const uint4*)(Qt + ((size_t)b * T_ + t0 + row) * D_ + k0 + ch * 8);
        *(uint4*)&sK[row][ch * 8] =
            *(const uint4*)(Km + ((size_t)b * S_ + row) * D_ + k0 + ch * 8);
        __syncthreads();
        short8 a[2], bb[2];
        #pragma unroll
        for (int i = 0; i < 2; ++i) {
            a[i]  = *(const short8*)&sQ[wm * 32 + i * 16 + lr][q * 8];
            bb[i] = *(const short8*)&sK[wn * 32 + i * 16 + lr][q * 8];
        }
        #pragma unroll
        for (int i = 0; i < 2; ++i)
            #pragma unroll
            for (int j = 0; j < 2; ++j)
                acc[i][j] = __builtin_amdgcn_mfma_f32_16x16x32_bf16(a[i], bb[j], acc[i][j], 0, 0, 0);
    }
    #pragma unroll
    for (int i = 0; i < 2; ++i)
        #pragma unroll
        for (int j = 0; j < 2; ++j)
            #pragma unroll
            for (int r = 0; r < 4; ++r) {
                float v = acc[i][j][r] * INV_SQRT_D;
                v = fminf(fmaxf(v, -SCORE_CLIP_), SCORE_CLIP_);
                ssc[wm * 32 + i * 16 + 4 * q + r][wn * 32 + j * 16 + lr] = v;
            }
    __syncthreads();
    // softmax over s: 4 threads per t-row (verified round-0 structure)
    const int srow = tid >> 2, qq = tid & 3;
    float vals[16];
    float mx = -1e30f;
    #pragma unroll
    for (int jj = 0; jj < 16; ++jj) {
        vals[jj] = ssc[srow][qq + (jj << 2)];
        mx = fmaxf(mx, vals[jj]);
    }
    mx = fmaxf(mx, __shfl_xor(mx, 1));
    mx = fmaxf(mx, __shfl_xor(mx, 2));
    float sum = 0.f;
    #pragma unroll
    for (int jj = 0; jj < 16; ++jj) {
        vals[jj] = expf(vals[jj] - mx);
        sum += vals[jj];
    }
    sum += __shfl_xor(sum, 1);
    sum += __shfl_xor(sum, 2);
    const int t = t0 + srow;
    const float mrow = (amask[b * T_ + t] > 0) ? 1.0f : 0.0f;
    const float inv = mrow / sum;
    #pragma unroll
    for (int jj = 0; jj < 16; ++jj)
        Wst[((size_t)b * S_ + qq + (jj << 2)) * T_ + t] = vals[jj] * inv;
}

// ---------------------------------------------------------------------------
// write[s][d] = sum_t Wst[s][t]*V[t][d];  M = clip(0.9M + 0.1 write, +-50)
__global__ __launch_bounds__(256) void k_write(
    const float* __restrict__ Wst, const unsigned short* __restrict__ Vtt,
    float* __restrict__ Mm)
{
    __shared__ unsigned short sA[64][40];
    __shared__ unsigned short sB[64][40];
    const int tid = threadIdx.x;
    const int d0 = blockIdx.x * 64;
    const int b = blockIdx.y;
    const int lane = tid & 63, w = tid >> 6;
    const int wm = w >> 1, wn = w & 1;
    const int q = lane >> 4, lr = lane & 15;
    const int row = tid >> 2, ch = tid & 3;
    f32x4 acc[2][2];
    #pragma unroll
    for (int i = 0; i < 2; ++i)
        #pragma unroll
        for (int j = 0; j < 2; ++j) acc[i][j] = (f32x4){0.f, 0.f, 0.f, 0.f};
    for (int k0 = 0; k0 < T_; k0 += 32) {
        __syncthreads();
        {
            const float* src = Wst + ((size_t)b * S_ + row) * T_ + k0 + ch * 8;
            const float4 x0 = *(const float4*)src, x1 = *(const float4*)(src + 4);
            uint4 u;
            u.x = pk2(x0.x, x0.y); u.y = pk2(x0.z, x0.w);
            u.z = pk2(x1.x, x1.y); u.w = pk2(x1.z, x1.w);
            *(uint4*)&sA[row][ch * 8] = u;
            *(uint4*)&sB[row][ch * 8] =
                *(const uint4*)(Vtt + ((size_t)b * D_ + d0 + row) * T_ + k0 + ch * 8);
        }
        __syncthreads();
        short8 a[2], bb[2];
        #pragma unroll
        for (int i = 0; i < 2; ++i) {
            a[i]  = *(const short8*)&sA[wm * 32 + i * 16 + lr][q * 8];
            bb[i] = *(const short8*)&sB[wn * 32 + i * 16 + lr][q * 8];
        }
        #pragma unroll
        for (int i = 0; i < 2; ++i)
            #pragma unroll
            for (int j = 0; j < 2; ++j)
                acc[i][j] = __builtin_amdgcn_mfma_f32_16x16x32_bf16(a[i], bb[j], acc[i][j], 0, 0, 0);
    }
    #pragma unroll
    for (int i = 0; i < 2; ++i)
        #pragma unroll
        for (int j = 0; j < 2; ++j)
            #pragma unroll
            for (int r = 0; r < 4; ++r) {
                const int s = wm * 32 + i * 16 + 4 * q + r;
                const int d = d0 + wn * 32 + j * 16 + lr;
                const size_t ix = ((size_t)b * S_ + s) * D_ + d;
                float m = Mm[ix];
                m = 0.9f * m + 0.1f * acc[i][j][r];
                Mm[ix] = fminf(fmaxf(m, -50.f), 50.f);
            }
}

// ---------------------------------------------------------------------------
// Wbar[b][s] = (sum_t Wst[b][s][t]) / max(valid_b, 1)
__global__ __launch_bounds__(256) void k_wbar(
    const float* __restrict__ Wst, const int* __restrict__ amask,
    float* __restrict__ Wbar)
{
    __shared__ float sv[256];
    const int b = blockIdx.x, tid = threadIdx.x;
    sv[tid] = ((amask[b * T_ + tid] > 0) ? 1.f : 0.f) +
              ((amask[b * T_ + 256 + tid] > 0) ? 1.f : 0.f);
    __syncthreads();
    for (int o = 128; o > 0; o >>= 1) {
        if (tid < o) sv[tid] += sv[tid + o];
        __syncthreads();
    }
    const float valid = fmaxf(sv[0], 1.0f);
    const int s = tid >> 2, part = tid & 3;
    const float* rowp = Wst + ((size_t)b * S_ + s) * T_ + part * 128;
    float sum = 0.f;
    for (int i = 0; i < 128; i += 4) {
        const float4 x = *(const float4*)(rowp + i);
        sum += x.x + x.y + x.z + x.w;
    }
    sum += __shfl_xor(sum, 1);
    sum += __shfl_xor(sum, 2);
    if (part == 0) Wbar[b * S_ + s] = sum / valid;
}

// ---------------------------------------------------------------------------
// pooled = Wbar @ M; LN; logits = pooled @ cls_w + cls_b; nan_to_num
__global__ __launch_bounds__(256) void k_head(
    const float* __restrict__ Wbar, const float* __restrict__ Mm,
    const float* __restrict__ ln_scale, const float* __restrict__ ln_bias,
    const float* __restrict__ cls_w, const float* __restrict__ cls_b,
    float* __restrict__ out)
{
    __shared__ float sw[64];
    __shared__ float sp[768];
    __shared__ float sred[4];
    __shared__ float sl[16][17];
    const int b = blockIdx.x, tid = threadIdx.x;
    if (tid < 64) sw[tid] = Wbar[b * S_ + tid];
    __syncthreads();
    float p[3] = {0.f, 0.f, 0.f};
    const float* Mb = Mm + (size_t)b * S_ * D_;
    for (int s = 0; s < S_; ++s) {
        const float wv = sw[s];
        const float* Mr = Mb + (size_t)s * D_;
        #pragma unroll
        for (int jj = 0; jj < 3; ++jj)
            p[jj] = fmaf(wv, Mr[tid + (jj << 8)], p[jj]);
    }
    float lsum = p[0] + p[1] + p[2];
    #pragma unroll
    for (int o = 1; o < 64; o <<= 1) lsum += __shfl_xor(lsum, o);
    if ((tid & 63) == 0) sred[tid >> 6] = lsum;
    __syncthreads();
    const float mean = (sred[0] + sred[1] + sred[2] + sred[3]) * (1.0f / 768.0f);
    float lv = 0.f;
    #pragma unroll
    for (int jj = 0; jj < 3; ++jj) { const float d = p[jj] - mean; lv += d * d; }
    #pragma unroll
    for (int o = 1; o < 64; o <<= 1) lv += __shfl_xor(lv, o);
    __syncthreads();
    if ((tid & 63) == 0) sred[tid >> 6] = lv;
    __syncthreads();
    const float var = (sred[0] + sred[1] + sred[2] + sred[3]) * (1.0f / 768.0f);
    const float inv = 1.0f / sqrtf(var + 1e-5f);
    #pragma unroll
    for (int jj = 0; jj < 3; ++jj) {
        const int d = tid + (jj << 8);
        sp[d] = (p[jj] - mean) * inv * ln_scale[d] + ln_bias[d];
    }
    __syncthreads();
    const int c = tid & 15, g = tid >> 4;
    float part = 0.f;
    const int d0 = g * 48;
    for (int d = d0; d < d0 + 48; ++d)
        part = fmaf(sp[d], cls_w[(size_t)d * C_ + c], part);
    sl[g][c] = part;
    __syncthreads();
    if (tid < 16) {
        float sum = cls_b[tid];
        #pragma unroll
        for (int g2 = 0; g2 < 16; ++g2) sum += sl[g2][tid];
        if (isnan(sum) || isinf(sum)) sum = 0.f;
        out[b * C_ + tid] = sum;
    }
}

// ---------------------------------------------------------------------------
extern "C" void kernel_launch(void* const* d_in, const int* in_sizes, int n_in,
                              void* d_out, int out_size, void* d_ws, size_t ws_size,
                              hipStream_t stream) {
    (void)in_sizes; (void)n_in; (void)out_size; (void)ws_size;
    const int*   ids      = (const int*)d_in[0];
    const int*   amask    = (const int*)d_in[1];
    const float* tok_emb  = (const float*)d_in[2];
    const float* pos_emb  = (const float*)d_in[3];
    const float* Wq       = (const float*)d_in[4];
    const float* Wk       = (const float*)d_in[5];
    const float* Wv       = (const float*)d_in[6];
    const float* mem_init = (const float*)d_in[7];
    const float* ln_scale = (const float*)d_in[8];
    const float* ln_bias  = (const float*)d_in[9];
    const float* cls_w    = (const float*)d_in[10];
    const float* cls_b    = (const float*)d_in[11];

    char* base = (char*)d_ws;
    unsigned short* Xb   = (unsigned short*)base;                 base += (size_t)B_ * T_ * D_ * 2;
    unsigned short* Wtq  = (unsigned short*)base;                 base += (size_t)D_ * D_ * 2;
    unsigned short* Wtk  = (unsigned short*)base;                 base += (size_t)D_ * D_ * 2;
    unsigned short* Wtv  = (unsigned short*)base;                 base += (size_t)D_ * D_ * 2;
    unsigned short* Qt   = (unsigned short*)base;                 base += (size_t)B_ * T_ * D_ * 2;
    unsigned short* Vtt  = (unsigned short*)base;                 base += (size_t)B_ * D_ * T_ * 2;
    unsigned short* Km   = (unsigned short*)base;                 base += (size_t)B_ * S_ * D_ * 2;
    float*          Mm   = (float*)base;                          base += (size_t)B_ * S_ * D_ * 4;
    float*          Wst  = (float*)base;                          base += (size_t)B_ * S_ * T_ * 4;
    float*          Wbar = (float*)base;                          base += (size_t)B_ * S_ * 4;

    k_prep<<<dim3(D_ * D_ / 256, 3), 256, 0, stream>>>(Wq, Wk, Wv, Wtq, Wtk, Wtv);
    k_initM<<<B_ * S_ * D_ / 4 / 256, 256, 0, stream>>>(mem_init, Mm);
    k_embed_x<<<B_ * T_ * D_ / 8 / 256, 256, 0, stream>>>(ids, tok_emb, pos_emb, Xb);
    k_qv<<<dim3(B_ * T_ / 128, D_ / 128), 256, 0, stream>>>(Xb, Wtq, Wtv, Qt, Vtt);
    for (int step = 0; step < 4; ++step) {
        k_km<<<dim3(D_ / 64, B_), 256, 0, stream>>>(Mm, Wtk, Km);
        k_scores<<<dim3(T_ / 64, B_), 256, 0, stream>>>(Qt, Km, amask, Wst);
        k_write<<<dim3(D_ / 64, B_), 256, 0, stream>>>(Wst, Vtt, Mm);
    }
    k_km<<<dim3(D_ / 64, B_), 256, 0, stream>>>(Mm, Wtk, Km);
    k_scores<<<dim3(T_ / 64, B_), 256, 0, stream>>>(Qt, Km, amask, Wst);
    k_wbar<<<B_, 256, 0, stream>>>(Wst, amask, Wbar);
    k_head<<<B_, 256, 0, stream>>>(Wbar, Mm, ln_scale, ln_bias, cls_w, cls_b,
                                   (float*)d_out);
}

// Round 5
// 428.013 us; speedup vs baseline: 3.1141x; 1.1375x over previous
//
#include <hip/hip_runtime.h>
#include <math.h>

#define B_ 32
#define T_ 512
#define D_ 768
#define S_ 64
#define C_ 16
#define INV_SQRT_D 0.03608439182435161f
#define SCORE_CLIP_ 20.0f

typedef __attribute__((ext_vector_type(8))) short short8;
typedef __attribute__((ext_vector_type(4))) float f32x4;

// RNE float->bf16
static __device__ __forceinline__ unsigned short f2bf(float f) {
    union { float f; unsigned u; } v; v.f = f;
    unsigned r = v.u + 0x7fffu + ((v.u >> 16) & 1u);
    return (unsigned short)(r >> 16);
}
static __device__ __forceinline__ unsigned pk2(float a, float b) {
    return (unsigned)f2bf(a) | ((unsigned)f2bf(b) << 16);
}
static __device__ __forceinline__ float bf2f(unsigned short h) {
    union { unsigned u; float f; } v; v.u = ((unsigned)h) << 16; return v.f;
}

// ---------------------------------------------------------------------------
// Wtv[n][k] = bf16(Wv[k][n])
__global__ __launch_bounds__(256) void k_prep(
    const float* __restrict__ Wv, unsigned short* __restrict__ Wtv)
{
    const int flat = blockIdx.x * 256 + threadIdx.x;   // n*768 + k
    const int n = flat / 768, k = flat - n * 768;
    Wtv[flat] = f2bf(Wv[(size_t)k * D_ + n]);
}

// ---------------------------------------------------------------------------
// Wqkt[n][k] = sum_j Wq[k][j] * Wk[n][j]  (= (Wq@Wk^T)[k][n], stored k-contig)
__global__ __launch_bounds__(256) void k_wqk(
    const float* __restrict__ Wq, const float* __restrict__ Wk,
    unsigned short* __restrict__ Wqkt)
{
    __shared__ unsigned short sA[64][40];   // Wk rows (n)
    __shared__ unsigned short sB[64][40];   // Wq rows (k = output col)
    const int tid = threadIdx.x;
    const int n0 = blockIdx.x * 64;
    const int c0 = blockIdx.y * 64;
    const int lane = tid & 63, w = tid >> 6;
    const int wm = w >> 1, wn = w & 1;
    const int q = lane >> 4, lr = lane & 15;
    const int row = tid >> 2, ch = tid & 3;
    f32x4 acc[2][2];
    #pragma unroll
    for (int i = 0; i < 2; ++i)
        #pragma unroll
        for (int j = 0; j < 2; ++j) acc[i][j] = (f32x4){0.f, 0.f, 0.f, 0.f};
    for (int j0 = 0; j0 < D_; j0 += 32) {
        __syncthreads();
        {
            const float* sa = Wk + (size_t)(n0 + row) * D_ + j0 + ch * 8;
            const float4 x0 = *(const float4*)sa, x1 = *(const float4*)(sa + 4);
            uint4 u;
            u.x = pk2(x0.x, x0.y); u.y = pk2(x0.z, x0.w);
            u.z = pk2(x1.x, x1.y); u.w = pk2(x1.z, x1.w);
            *(uint4*)&sA[row][ch * 8] = u;
            const float* sb = Wq + (size_t)(c0 + row) * D_ + j0 + ch * 8;
            const float4 y0 = *(const float4*)sb, y1 = *(const float4*)(sb + 4);
            uint4 v;
            v.x = pk2(y0.x, y0.y); v.y = pk2(y0.z, y0.w);
            v.z = pk2(y1.x, y1.y); v.w = pk2(y1.z, y1.w);
            *(uint4*)&sB[row][ch * 8] = v;
        }
        __syncthreads();
        short8 a[2], bb[2];
        #pragma unroll
        for (int i = 0; i < 2; ++i) {
            a[i]  = *(const short8*)&sA[wm * 32 + i * 16 + lr][q * 8];
            bb[i] = *(const short8*)&sB[wn * 32 + i * 16 + lr][q * 8];
        }
        #pragma unroll
        for (int i = 0; i < 2; ++i)
            #pragma unroll
            for (int j = 0; j < 2; ++j)
                acc[i][j] = __builtin_amdgcn_mfma_f32_16x16x32_bf16(a[i], bb[j], acc[i][j], 0, 0, 0);
    }
    #pragma unroll
    for (int i = 0; i < 2; ++i)
        #pragma unroll
        for (int j = 0; j < 2; ++j)
            #pragma unroll
            for (int r = 0; r < 4; ++r) {
                const int n = n0 + wm * 32 + i * 16 + 4 * q + r;
                const int k = c0 + wn * 32 + j * 16 + lr;
                Wqkt[(size_t)n * D_ + k] = f2bf(acc[i][j][r]);
            }
}

// ---------------------------------------------------------------------------
// M[b][s][d] = mem_init[s][d] (fp32 master + bf16 shadow)
__global__ __launch_bounds__(256) void k_initM(const float* __restrict__ mem_init,
                                               float* __restrict__ Mm,
                                               unsigned short* __restrict__ Mb) {
    const int i = blockIdx.x * 256 + threadIdx.x;        // float4 index
    const int per = S_ * D_ / 4;
    const float4 v = *(const float4*)(mem_init + (size_t)(i % per) * 4);
    *(float4*)(Mm + (size_t)i * 4) = v;
    uint2 u; u.x = pk2(v.x, v.y); u.y = pk2(v.z, v.w);
    *(uint2*)(Mb + (size_t)i * 4) = u;
}

// ---------------------------------------------------------------------------
// X[r][d] = bf16(tok_emb[ids[r]][d] + pos_emb[r%512][d])
__global__ __launch_bounds__(256) void k_embed_x(
    const int* __restrict__ ids, const float* __restrict__ tok_emb,
    const float* __restrict__ pos_emb, unsigned short* __restrict__ Xb)
{
    const int idx = blockIdx.x * 256 + threadIdx.x;      // chunk of 8 elems
    const int r = idx / 96, c = (idx - r * 96) * 8;
    const int id = ids[r], tp = r & (T_ - 1);
    const float* te = tok_emb + (size_t)id * D_ + c;
    const float* pe = pos_emb + (size_t)tp * D_ + c;
    const float4 a0 = *(const float4*)te, a1 = *(const float4*)(te + 4);
    const float4 p0 = *(const float4*)pe, p1 = *(const float4*)(pe + 4);
    uint4 u;
    u.x = pk2(a0.x + p0.x, a0.y + p0.y);
    u.y = pk2(a0.z + p0.z, a0.w + p0.w);
    u.z = pk2(a1.x + p1.x, a1.y + p1.y);
    u.w = pk2(a1.z + p1.z, a1.w + p1.w);
    *(uint4*)(Xb + (size_t)idx * 8) = u;
}

// ---------------------------------------------------------------------------
// Dual GEMM: QK[t][n] = X@Wqkt (natural), Vtt[b][d][t] = (X@Wv)^T. 128x128 tile.
__global__ __launch_bounds__(256) void k_qv(
    const unsigned short* __restrict__ Xb, const unsigned short* __restrict__ Wqkt,
    const unsigned short* __restrict__ Wtv, unsigned short* __restrict__ QK,
    unsigned short* __restrict__ Vtt)
{
    __shared__ unsigned short sX[128][40];
    __shared__ unsigned short sQ[128][40];
    __shared__ unsigned short sV[128][40];
    const int tid = threadIdx.x;
    const int row0 = blockIdx.x * 128;   // token rows
    const int col0 = blockIdx.y * 128;   // n cols
    const int lane = tid & 63, w = tid >> 6;
    const int wm = w >> 1, wn = w & 1;
    const int q = lane >> 4, lr = lane & 15;
    f32x4 accq[4][4], accv[4][4];
    #pragma unroll
    for (int i = 0; i < 4; ++i)
        #pragma unroll
        for (int j = 0; j < 4; ++j) {
            accq[i][j] = (f32x4){0.f, 0.f, 0.f, 0.f};
            accv[i][j] = (f32x4){0.f, 0.f, 0.f, 0.f};
        }
    for (int k0 = 0; k0 < D_; k0 += 32) {
        __syncthreads();
        #pragma unroll
        for (int cc = 0; cc < 2; ++cc) {
            const int c = tid + cc * 256;
            const int row = c >> 2, ch = c & 3;
            *(uint4*)&sX[row][ch * 8] =
                *(const uint4*)(Xb + (size_t)(row0 + row) * D_ + k0 + ch * 8);
            *(uint4*)&sQ[row][ch * 8] =
                *(const uint4*)(Wqkt + (size_t)(col0 + row) * D_ + k0 + ch * 8);
            *(uint4*)&sV[row][ch * 8] =
                *(const uint4*)(Wtv + (size_t)(col0 + row) * D_ + k0 + ch * 8);
        }
        __syncthreads();
        short8 a[4], bq[4], bv[4];
        #pragma unroll
        for (int i = 0; i < 4; ++i) {
            a[i]  = *(const short8*)&sX[wm * 64 + i * 16 + lr][q * 8];
            bq[i] = *(const short8*)&sQ[wn * 64 + i * 16 + lr][q * 8];
            bv[i] = *(const short8*)&sV[wn * 64 + i * 16 + lr][q * 8];
        }
        #pragma unroll
        for (int i = 0; i < 4; ++i)
            #pragma unroll
            for (int j = 0; j < 4; ++j) {
                accq[i][j] = __builtin_amdgcn_mfma_f32_16x16x32_bf16(a[i], bq[j], accq[i][j], 0, 0, 0);
                accv[i][j] = __builtin_amdgcn_mfma_f32_16x16x32_bf16(a[i], bv[j], accv[i][j], 0, 0, 0);
            }
    }
    const int b = row0 >> 9;
    #pragma unroll
    for (int i = 0; i < 4; ++i)
        #pragma unroll
        for (int j = 0; j < 4; ++j) {
            const int gr = row0 + wm * 64 + i * 16 + 4 * q;   // token row
            const int gc = col0 + wn * 64 + j * 16 + lr;      // n col
            #pragma unroll
            for (int r = 0; r < 4; ++r)
                QK[(size_t)(gr + r) * D_ + gc] = f2bf(accq[i][j][r]);
            uint2 u;
            u.x = pk2(accv[i][j][0], accv[i][j][1]);
            u.y = pk2(accv[i][j][2], accv[i][j][3]);
            const int t = (gr & (T_ - 1));
            *(uint2*)(Vtt + ((size_t)b * D_ + gc) * T_ + t) = u;
        }
}

// ---------------------------------------------------------------------------
// scores[t][s] = clip(QK[b,t,:]·Mb[b,s,:] * inv_sqrt_d) -> softmax over s
// -> Wsb[b][s][t] (bf16, transposed)
__global__ __launch_bounds__(256) void k_scores(
    const unsigned short* __restrict__ QK, const unsigned short* __restrict__ Mb,
    const int* __restrict__ amask, unsigned short* __restrict__ Wsb)
{
    __shared__ unsigned short sQ[64][40];
    __shared__ unsigned short sK[64][40];
    __shared__ float ssc[64][65];
    const int tid = threadIdx.x;
    const int t0 = blockIdx.x * 64;
    const int b = blockIdx.y;
    const int lane = tid & 63, w = tid >> 6;
    const int wm = w >> 1, wn = w & 1;
    const int q = lane >> 4, lr = lane & 15;
    const int row = tid >> 2, ch = tid & 3;
    f32x4 acc[2][2];
    #pragma unroll
    for (int i = 0; i < 2; ++i)
        #pragma unroll
        for (int j = 0; j < 2; ++j) acc[i][j] = (f32x4){0.f, 0.f, 0.f, 0.f};
    for (int k0 = 0; k0 < D_; k0 += 32) {
        __syncthreads();
        *(uint4*)&sQ[row][ch * 8] =
            *(const uint4*)(QK + ((size_t)b * T_ + t0 + row) * D_ + k0 + ch * 8);
        *(uint4*)&sK[row][ch * 8] =
            *(const uint4*)(Mb + ((size_t)b * S_ + row) * D_ + k0 + ch * 8);
        __syncthreads();
        short8 a[2], bb[2];
        #pragma unroll
        for (int i = 0; i < 2; ++i) {
            a[i]  = *(const short8*)&sQ[wm * 32 + i * 16 + lr][q * 8];
            bb[i] = *(const short8*)&sK[wn * 32 + i * 16 + lr][q * 8];
        }
        #pragma unroll
        for (int i = 0; i < 2; ++i)
            #pragma unroll
            for (int j = 0; j < 2; ++j)
                acc[i][j] = __builtin_amdgcn_mfma_f32_16x16x32_bf16(a[i], bb[j], acc[i][j], 0, 0, 0);
    }
    #pragma unroll
    for (int i = 0; i < 2; ++i)
        #pragma unroll
        for (int j = 0; j < 2; ++j)
            #pragma unroll
            for (int r = 0; r < 4; ++r) {
                float v = acc[i][j][r] * INV_SQRT_D;
                v = fminf(fmaxf(v, -SCORE_CLIP_), SCORE_CLIP_);
                ssc[wm * 32 + i * 16 + 4 * q + r][wn * 32 + j * 16 + lr] = v;
            }
    __syncthreads();
    // softmax over s: 4 threads per t-row
    const int srow = tid >> 2, qq = tid & 3;
    float vals[16];
    float mx = -1e30f;
    #pragma unroll
    for (int jj = 0; jj < 16; ++jj) {
        vals[jj] = ssc[srow][qq + (jj << 2)];
        mx = fmaxf(mx, vals[jj]);
    }
    mx = fmaxf(mx, __shfl_xor(mx, 1));
    mx = fmaxf(mx, __shfl_xor(mx, 2));
    float sum = 0.f;
    #pragma unroll
    for (int jj = 0; jj < 16; ++jj) {
        vals[jj] = expf(vals[jj] - mx);
        sum += vals[jj];
    }
    sum += __shfl_xor(sum, 1);
    sum += __shfl_xor(sum, 2);
    const int t = t0 + srow;
    const float mrow = (amask[b * T_ + t] > 0) ? 1.0f : 0.0f;
    const float inv = mrow / sum;
    #pragma unroll
    for (int jj = 0; jj < 16; ++jj)
        Wsb[((size_t)b * S_ + qq + (jj << 2)) * T_ + t] = f2bf(vals[jj] * inv);
}

// ---------------------------------------------------------------------------
// write[s][d] = sum_t Wsb[s][t]*V[t][d];  M = clip(0.9M + 0.1 write, +-50)
// updates fp32 master Mm and bf16 shadow Mb
__global__ __launch_bounds__(256) void k_write(
    const unsigned short* __restrict__ Wsb, const unsigned short* __restrict__ Vtt,
    float* __restrict__ Mm, unsigned short* __restrict__ Mb)
{
    __shared__ unsigned short sA[64][40];
    __shared__ unsigned short sB[64][40];
    const int tid = threadIdx.x;
    const int d0 = blockIdx.x * 64;
    const int b = blockIdx.y;
    const int lane = tid & 63, w = tid >> 6;
    const int wm = w >> 1, wn = w & 1;
    const int q = lane >> 4, lr = lane & 15;
    const int row = tid >> 2, ch = tid & 3;
    f32x4 acc[2][2];
    #pragma unroll
    for (int i = 0; i < 2; ++i)
        #pragma unroll
        for (int j = 0; j < 2; ++j) acc[i][j] = (f32x4){0.f, 0.f, 0.f, 0.f};
    for (int k0 = 0; k0 < T_; k0 += 32) {
        __syncthreads();
        *(uint4*)&sA[row][ch * 8] =
            *(const uint4*)(Wsb + ((size_t)b * S_ + row) * T_ + k0 + ch * 8);
        *(uint4*)&sB[row][ch * 8] =
            *(const uint4*)(Vtt + ((size_t)b * D_ + d0 + row) * T_ + k0 + ch * 8);
        __syncthreads();
        short8 a[2], bb[2];
        #pragma unroll
        for (int i = 0; i < 2; ++i) {
            a[i]  = *(const short8*)&sA[wm * 32 + i * 16 + lr][q * 8];
            bb[i] = *(const short8*)&sB[wn * 32 + i * 16 + lr][q * 8];
        }
        #pragma unroll
        for (int i = 0; i < 2; ++i)
            #pragma unroll
            for (int j = 0; j < 2; ++j)
                acc[i][j] = __builtin_amdgcn_mfma_f32_16x16x32_bf16(a[i], bb[j], acc[i][j], 0, 0, 0);
    }
    #pragma unroll
    for (int i = 0; i < 2; ++i)
        #pragma unroll
        for (int j = 0; j < 2; ++j)
            #pragma unroll
            for (int r = 0; r < 4; ++r) {
                const int s = wm * 32 + i * 16 + 4 * q + r;
                const int d = d0 + wn * 32 + j * 16 + lr;
                const size_t ix = ((size_t)b * S_ + s) * D_ + d;
                float m = Mm[ix];
                m = 0.9f * m + 0.1f * acc[i][j][r];
                m = fminf(fmaxf(m, -50.f), 50.f);
                Mm[ix] = m;
                Mb[ix] = f2bf(m);
            }
}

// ---------------------------------------------------------------------------
// Wbar[b][s] = (sum_t Wsb[b][s][t]) / max(valid_b, 1)
__global__ __launch_bounds__(256) void k_wbar(
    const unsigned short* __restrict__ Wsb, const int* __restrict__ amask,
    float* __restrict__ Wbar)
{
    __shared__ float sv[256];
    const int b = blockIdx.x, tid = threadIdx.x;
    sv[tid] = ((amask[b * T_ + tid] > 0) ? 1.f : 0.f) +
              ((amask[b * T_ + 256 + tid] > 0) ? 1.f : 0.f);
    __syncthreads();
    for (int o = 128; o > 0; o >>= 1) {
        if (tid < o) sv[tid] += sv[tid + o];
        __syncthreads();
    }
    const float valid = fmaxf(sv[0], 1.0f);
    const int s = tid >> 2, part = tid & 3;
    const unsigned short* rowp = Wsb + ((size_t)b * S_ + s) * T_ + part * 128;
    float sum = 0.f;
    for (int i = 0; i < 128; i += 8) {
        const short8 x = *(const short8*)(rowp + i);
        #pragma unroll
        for (int j = 0; j < 8; ++j) sum += bf2f((unsigned short)x[j]);
    }
    sum += __shfl_xor(sum, 1);
    sum += __shfl_xor(sum, 2);
    if (part == 0) Wbar[b * S_ + s] = sum / valid;
}

// ---------------------------------------------------------------------------
// pooled = Wbar @ M; LN; logits = pooled @ cls_w + cls_b; nan_to_num
__global__ __launch_bounds__(256) void k_head(
    const float* __restrict__ Wbar, const float* __restrict__ Mm,
    const float* __restrict__ ln_scale, const float* __restrict__ ln_bias,
    const float* __restrict__ cls_w, const float* __restrict__ cls_b,
    float* __restrict__ out)
{
    __shared__ float sw[64];
    __shared__ float sp[768];
    __shared__ float sred[4];
    __shared__ float sl[16][17];
    const int b = blockIdx.x, tid = threadIdx.x;
    if (tid < 64) sw[tid] = Wbar[b * S_ + tid];
    __syncthreads();
    float p[3] = {0.f, 0.f, 0.f};
    const float* Mb = Mm + (size_t)b * S_ * D_;
    for (int s = 0; s < S_; ++s) {
        const float wv = sw[s];
        const float* Mr = Mb + (size_t)s * D_;
        #pragma unroll
        for (int jj = 0; jj < 3; ++jj)
            p[jj] = fmaf(wv, Mr[tid + (jj << 8)], p[jj]);
    }
    float lsum = p[0] + p[1] + p[2];
    #pragma unroll
    for (int o = 1; o < 64; o <<= 1) lsum += __shfl_xor(lsum, o);
    if ((tid & 63) == 0) sred[tid >> 6] = lsum;
    __syncthreads();
    const float mean = (sred[0] + sred[1] + sred[2] + sred[3]) * (1.0f / 768.0f);
    float lv = 0.f;
    #pragma unroll
    for (int jj = 0; jj < 3; ++jj) { const float d = p[jj] - mean; lv += d * d; }
    #pragma unroll
    for (int o = 1; o < 64; o <<= 1) lv += __shfl_xor(lv, o);
    __syncthreads();
    if ((tid & 63) == 0) sred[tid >> 6] = lv;
    __syncthreads();
    const float var = (sred[0] + sred[1] + sred[2] + sred[3]) * (1.0f / 768.0f);
    const float inv = 1.0f / sqrtf(var + 1e-5f);
    #pragma unroll
    for (int jj = 0; jj < 3; ++jj) {
        const int d = tid + (jj << 8);
        sp[d] = (p[jj] - mean) * inv * ln_scale[d] + ln_bias[d];
    }
    __syncthreads();
    const int c = tid & 15, g = tid >> 4;
    float part = 0.f;
    const int d0 = g * 48;
    for (int d = d0; d < d0 + 48; ++d)
        part = fmaf(sp[d], cls_w[(size_t)d * C_ + c], part);
    sl[g][c] = part;
    __syncthreads();
    if (tid < 16) {
        float sum = cls_b[tid];
        #pragma unroll
        for (int g2 = 0; g2 < 16; ++g2) sum += sl[g2][tid];
        if (isnan(sum) || isinf(sum)) sum = 0.f;
        out[b * C_ + tid] = sum;
    }
}

// ---------------------------------------------------------------------------
extern "C" void kernel_launch(void* const* d_in, const int* in_sizes, int n_in,
                              void* d_out, int out_size, void* d_ws, size_t ws_size,
                              hipStream_t stream) {
    (void)in_sizes; (void)n_in; (void)out_size; (void)ws_size;
    const int*   ids      = (const int*)d_in[0];
    const int*   amask    = (const int*)d_in[1];
    const float* tok_emb  = (const float*)d_in[2];
    const float* pos_emb  = (const float*)d_in[3];
    const float* Wq       = (const float*)d_in[4];
    const float* Wk       = (const float*)d_in[5];
    const float* Wv       = (const float*)d_in[6];
    const float* mem_init = (const float*)d_in[7];
    const float* ln_scale = (const float*)d_in[8];
    const float* ln_bias  = (const float*)d_in[9];
    const float* cls_w    = (const float*)d_in[10];
    const float* cls_b    = (const float*)d_in[11];

    char* base = (char*)d_ws;
    unsigned short* Xb   = (unsigned short*)base;   base += (size_t)B_ * T_ * D_ * 2;
    unsigned short* Wtv  = (unsigned short*)base;   base += (size_t)D_ * D_ * 2;
    unsigned short* Wqkt = (unsigned short*)base;   base += (size_t)D_ * D_ * 2;
    unsigned short* QK   = (unsigned short*)base;   base += (size_t)B_ * T_ * D_ * 2;
    unsigned short* Vtt  = (unsigned short*)base;   base += (size_t)B_ * D_ * T_ * 2;
    unsigned short* Mb   = (unsigned short*)base;   base += (size_t)B_ * S_ * D_ * 2;
    unsigned short* Wsb  = (unsigned short*)base;   base += (size_t)B_ * S_ * T_ * 2;
    float*          Mm   = (float*)base;            base += (size_t)B_ * S_ * D_ * 4;
    float*          Wbar = (float*)base;            base += (size_t)B_ * S_ * 4;

    k_prep<<<D_ * D_ / 256, 256, 0, stream>>>(Wv, Wtv);
    k_wqk<<<dim3(D_ / 64, D_ / 64), 256, 0, stream>>>(Wq, Wk, Wqkt);
    k_initM<<<B_ * S_ * D_ / 4 / 256, 256, 0, stream>>>(mem_init, Mm, Mb);
    k_embed_x<<<B_ * T_ * D_ / 8 / 256, 256, 0, stream>>>(ids, tok_emb, pos_emb, Xb);
    k_qv<<<dim3(B_ * T_ / 128, D_ / 128), 256, 0, stream>>>(Xb, Wqkt, Wtv, QK, Vtt);
    for (int step = 0; step < 4; ++step) {
        k_scores<<<dim3(T_ / 64, B_), 256, 0, stream>>>(QK, Mb, amask, Wsb);
        k_write<<<dim3(D_ / 64, B_), 256, 0, stream>>>(Wsb, Vtt, Mm, Mb);
    }
    k_scores<<<dim3(T_ / 64, B_), 256, 0, stream>>>(QK, Mb, amask, Wsb);
    k_wbar<<<B_, 256, 0, stream>>>(Wsb, amask, Wbar);
    k_head<<<B_, 256, 0, stream>>>(Wbar, Mm, ln_scale, ln_bias, cls_w, cls_b,
                                   (float*)d_out);
}